// Round 9
// baseline (100.964 us; speedup 1.0000x reference)
//
#include <hip/hip_runtime.h>

#define MAX_BS 128
#define INV4PI 0.07957747154594767f

__device__ __forceinline__ float bcast(float v, int j) {
    // Uniform lane index -> v_readlane_b32 into SGPR, free broadcast.
    return __int_as_float(__builtin_amdgcn_readlane(__float_as_int(v), j));
}

// One block per pair, 128 threads = 2 waves; lane t = target row t.
// The ENTIRE source box lives in wave registers: lane L holds sources L and
// L+64 ({x,y,z,w*INV4PI} = 8 VGPRs). Inner loop broadcasts source j via
// v_readlane (no memory op, no waitcnt, no barrier in the loop).
// NOTE: individual dead rows must not return (their lanes carry source
// registers); only whole waves exit. Row mask applies at the atomic only.
__global__ __launch_bounds__(128) void fmm_lane_kernel(
    const float* __restrict__ q_vec,    // [NBOXES][MAX_BS]
    const float* __restrict__ XX,       // [NBOXES][MAX_BS][3]
    const int*   __restrict__ bs_list,  // [NBOXES]
    const int2*  __restrict__ uq_boxes, // [NPAIRS]
    float*       __restrict__ out)      // [NBOXES][MAX_BS]
{
    const int p = blockIdx.x;
    const int t = threadIdx.x;          // row id (0..127)
    const int lane = t & 63;

    const int2 uq = uq_boxes[p];
    const int u = __builtin_amdgcn_readfirstlane(uq.x);
    const int q = __builtin_amdgcn_readfirstlane(uq.y);
    const int bs_u = bs_list[u];
    const int bs_q = bs_list[q];

    // Whole-wave exits only: wave1 if bs_u<=64; both waves if bs_u==0.
    if ((t & 64) >= bs_u || bs_q == 0) return;

    // Preload sources: lane L -> source L (s0) and L+64 (s1). All 128 slots
    // of XX/q_vec exist regardless of bs_q, so loads are always in-bounds.
    const float* __restrict__ Xq = XX + (size_t)q * (MAX_BS * 3);
    const float* __restrict__ qv = q_vec + (size_t)q * MAX_BS;
    const float s0x = Xq[3 * lane + 0];
    const float s0y = Xq[3 * lane + 1];
    const float s0z = Xq[3 * lane + 2];
    const float s0w = qv[lane] * INV4PI;
    const float s1x = Xq[3 * (lane + 64) + 0];
    const float s1y = Xq[3 * (lane + 64) + 1];
    const float s1z = Xq[3 * (lane + 64) + 2];
    const float s1w = qv[lane + 64] * INV4PI;

    // Own target row (garbage for dead rows t>=bs_u; masked at the store).
    const float* __restrict__ Xu = XX + (size_t)u * (MAX_BS * 3);
    const float xu = Xu[3 * t + 0];
    const float yu = Xu[3 * t + 1];
    const float zu = Xu[3 * t + 2];

    const int n0 = (bs_q < 64) ? bs_q : 64;
    float acc = 0.0f;

    if (u != q) {
        // Distinct boxes: r2 > 0 always (continuous random coords).
#pragma unroll 4
        for (int j = 0; j < n0; ++j) {
            const float sx = bcast(s0x, j), sy = bcast(s0y, j);
            const float sz = bcast(s0z, j), sw = bcast(s0w, j);
            const float dx = xu - sx, dy = yu - sy, dz = zu - sz;
            const float r2 = fmaf(dx, dx, fmaf(dy, dy, dz * dz));
            acc = fmaf(sw, __builtin_amdgcn_rsqf(r2), acc);
        }
#pragma unroll 4
        for (int j = 64; j < bs_q; ++j) {
            const float sx = bcast(s1x, j - 64), sy = bcast(s1y, j - 64);
            const float sz = bcast(s1z, j - 64), sw = bcast(s1w, j - 64);
            const float dx = xu - sx, dy = yu - sy, dz = zu - sz;
            const float r2 = fmaf(dx, dx, fmaf(dy, dy, dz * dz));
            acc = fmaf(sw, __builtin_amdgcn_rsqf(r2), acc);
        }
    } else {
        // Self pair (~2/8192, block-uniform): guard exact self-interaction.
        for (int j = 0; j < n0; ++j) {
            const float sx = bcast(s0x, j), sy = bcast(s0y, j);
            const float sz = bcast(s0z, j), sw = bcast(s0w, j);
            const float dx = xu - sx, dy = yu - sy, dz = zu - sz;
            const float r2 = fmaf(dx, dx, fmaf(dy, dy, dz * dz));
            float rv = __builtin_amdgcn_rsqf(r2);
            rv = (r2 > 0.0f) ? rv : 0.0f;
            acc = fmaf(sw, rv, acc);
        }
        for (int j = 64; j < bs_q; ++j) {
            const float sx = bcast(s1x, j - 64), sy = bcast(s1y, j - 64);
            const float sz = bcast(s1z, j - 64), sw = bcast(s1w, j - 64);
            const float dx = xu - sx, dy = yu - sy, dz = zu - sz;
            const float r2 = fmaf(dx, dx, fmaf(dy, dy, dz * dz));
            float rv = __builtin_amdgcn_rsqf(r2);
            rv = (r2 > 0.0f) ? rv : 0.0f;
            acc = fmaf(sw, rv, acc);
        }
    }

    // Exact row mask at the store only.
    if (t < bs_u) atomicAdd(out + (size_t)u * MAX_BS + t, acc);
}

extern "C" void kernel_launch(void* const* d_in, const int* in_sizes, int n_in,
                              void* d_out, int out_size, void* d_ws, size_t ws_size,
                              hipStream_t stream) {
    const float* q_vec    = (const float*)d_in[0];
    const float* XX_list  = (const float*)d_in[1];
    const int*   bs_list  = (const int*)d_in[2];
    const int2*  uq_boxes = (const int2*)d_in[3];
    float* out = (float*)d_out;

    const int npairs = in_sizes[3] / 2;   // 8192

    // Atomic accumulation needs a zeroed output (harness poisons with 0xAA).
    hipMemsetAsync(d_out, 0, (size_t)out_size * sizeof(float), stream);

    fmm_lane_kernel<<<npairs, 128, 0, stream>>>(
        q_vec, XX_list, bs_list, uq_boxes, out);
}

// Round 10
// 87.924 us; speedup vs baseline: 1.1483x; 1.1483x over previous
//
#include <hip/hip_runtime.h>

#define MAX_BS 128
#define INV4PI 0.07957747154594767f

// One WAVE per (pair, row-half): block = 64 threads = 1 wave.
// blockIdx.x = 2*p + h; lane t owns target row h*64+t of pair p's u box.
// Source box read through the scalar pipe (uniform addresses): no LDS, no
// barrier, no in-loop waitcnt beyond the s_load stream. Identical math to R5.
__global__ __launch_bounds__(64) void fmm_wave_kernel(
    const float* __restrict__ q_vec,    // [NBOXES][MAX_BS]
    const float* __restrict__ XX,       // [NBOXES][MAX_BS][3]
    const int*   __restrict__ bs_list,  // [NBOXES]
    const int2*  __restrict__ uq_boxes, // [NPAIRS]
    float*       __restrict__ out)      // [NBOXES][MAX_BS]
{
    const int b = blockIdx.x;
    const int p = b >> 1;               // pair id
    const int t = (b & 1) * 64 + threadIdx.x;   // target row 0..127

    const int2 uq = uq_boxes[p];
    const int u = __builtin_amdgcn_readfirstlane(uq.x);
    const int q = __builtin_amdgcn_readfirstlane(uq.y);
    const int bs_u = bs_list[u];
    const int bs_q = bs_list[q];

    if (t >= bs_u || bs_q == 0) return; // exact row mask; dead wave = dead block

    // Own target point (lane-varying vector loads).
    const float* __restrict__ Xu = XX + (size_t)u * (MAX_BS * 3);
    const float xu = Xu[3 * t + 0];
    const float yu = Xu[3 * t + 1];
    const float zu = Xu[3 * t + 2];

    // Uniform source pointers -> scalar-pipe loads in the loop.
    const float* __restrict__ Xq = XX + (size_t)q * (MAX_BS * 3);
    const float* __restrict__ qv = q_vec + (size_t)q * MAX_BS;

    float acc = 0.0f;
    if (u != q) {
        // Distinct boxes: r2 > 0 always (continuous random coords).
#pragma unroll 8
        for (int j = 0; j < bs_q; ++j) {
            const float sx = Xq[3 * j + 0];   // uniform -> s_load, free bcast
            const float sy = Xq[3 * j + 1];
            const float sz = Xq[3 * j + 2];
            const float w  = qv[j];
            const float dx = xu - sx;
            const float dy = yu - sy;
            const float dz = zu - sz;
            const float r2 = fmaf(dx, dx, fmaf(dy, dy, dz * dz));
            acc = fmaf(w, __builtin_amdgcn_rsqf(r2), acc);
        }
    } else {
        // Self pair (~2/8192, block-uniform): guard exact self-interaction.
#pragma unroll 4
        for (int j = 0; j < bs_q; ++j) {
            const float sx = Xq[3 * j + 0];
            const float sy = Xq[3 * j + 1];
            const float sz = Xq[3 * j + 2];
            const float w  = qv[j];
            const float dx = xu - sx;
            const float dy = yu - sy;
            const float dz = zu - sz;
            const float r2 = fmaf(dx, dx, fmaf(dy, dy, dz * dz));
            float rv = __builtin_amdgcn_rsqf(r2);
            rv = (r2 > 0.0f) ? rv : 0.0f;
            acc = fmaf(w, rv, acc);
        }
    }

    atomicAdd(out + (size_t)u * MAX_BS + t, acc * INV4PI);
}

extern "C" void kernel_launch(void* const* d_in, const int* in_sizes, int n_in,
                              void* d_out, int out_size, void* d_ws, size_t ws_size,
                              hipStream_t stream) {
    const float* q_vec    = (const float*)d_in[0];
    const float* XX_list  = (const float*)d_in[1];
    const int*   bs_list  = (const int*)d_in[2];
    const int2*  uq_boxes = (const int2*)d_in[3];
    float* out = (float*)d_out;

    const int npairs = in_sizes[3] / 2;   // 8192

    // Atomic accumulation needs a zeroed output (harness poisons with 0xAA).
    hipMemsetAsync(d_out, 0, (size_t)out_size * sizeof(float), stream);

    fmm_wave_kernel<<<npairs * 2, 64, 0, stream>>>(
        q_vec, XX_list, bs_list, uq_boxes, out);
}